// Round 7
// baseline (64.322 us; speedup 1.0000x reference)
//
#include <hip/hip_runtime.h>

typedef _Float16 half8 __attribute__((ext_vector_type(8)));
typedef float    f32x4 __attribute__((ext_vector_type(4)));

#define NLEN   8388608
#define KTAPS  257
#define MPAD   256
#define OUTLEN (NLEN + MPAD)        /* 8388864 */
#define TPB    256
#define BT     2048                 /* complex outputs per tile (2 16x16 tiles/wave) */
#define NTILES ((OUTLEN + BT - 1) / BT)   /* 4097 */
#define TPT    4                    /* tiles per block, double-buffered pipeline */
#define NBLKP  ((NTILES + TPT - 1) / TPT) /* 1025 */
#define NCH    9                    /* K chunks of 32 -> GEMM-K = 288 */
#define XELEM  (BT + 288)           /* staged elems per component: 2336 */
#define XSLOT  (XELEM / 8)          /* 292 16B slots */
#define XPAD   300                  /* + swizzle margin */
#define AFSLOT (2 * NCH * 64)       /* 1152 half8 slots = 18432 B */

__device__ __forceinline__ int swz(int t) { return t ^ ((t >> 3) & 7); }

/* ---------- pre-kernel: weight-fragment table in global ws ---------- */
__global__ __launch_bounds__(TPB) void build_af(
    const float* __restrict__ wr, const float* __restrict__ wi,
    half8* __restrict__ af)
{
    for (int i = threadIdx.x; i < AFSLOT; i += TPB) {
        const int comp = i / (NCH * 64);
        const int rem  = i % (NCH * 64);
        const int c    = rem >> 6;
        const int l    = rem & 63;
        const int row  = l & 15;
        const int jb   = 32 * c + 8 * (l >> 4);
        const float* wp = comp ? wi : wr;
        half8 v;
        #pragma unroll
        for (int e = 0; e < 8; ++e) {
            const int k = jb + e - row;
            const float f = (k >= 0 && k < KTAPS) ? wp[k] : 0.0f;
            v[e] = (_Float16)f;
        }
        af[i] = v;
    }
}

/* ---------- main: 4 tiles/block, double-buffered LDS, T14 reg-staging ---------- */
__global__ __launch_bounds__(TPB, 4) void cconv_db(
    const float* __restrict__ xr, const float* __restrict__ xi,
    const half8* __restrict__ af, float* __restrict__ out)
{
    __shared__ half8 lx[2][2][XPAD];     /* [buf][comp][slot] */

    const int tid   = threadIdx.x;
    const int wv    = tid >> 6;
    const int lane  = tid & 63;
    const int n15   = lane & 15;
    const int lg    = lane >> 4;
    const int T0    = tid;               /* slot 0: always valid (292 > 256)   */
    const int T1    = tid + TPB;         /* slot 1: valid for tid < 36         */
    const bool hasT1 = (T1 < XSLOT);
    const int tile0 = blockIdx.x * TPT;
    const int ntile = (NTILES - tile0 < TPT) ? (NTILES - tile0) : TPT;

    const int sT0   = 64 * wv + 2 * n15 + lg;   /* base 16B slot for this lane */
    const half8* afr = af + lane;               /* comp 0, chunk c at +64*c    */
    const half8* afi = af + NCH * 64 + lane;    /* comp 1                      */

    /* staged-load registers (named -> stay in VGPRs, rule #20) */
    f32x4 A0a, A0b, B0a, B0b;            /* slot T0: xr pair, xi pair */
    f32x4 A1a, A1b, B1a, B1b;            /* slot T1 */

    /* issue global loads for one tile's stage region (interior fast path) */
    auto issue_loads = [&](int tile, bool& inter) {
        const int xbase = tile * BT - MPAD;
        inter = (xbase >= 0) && (xbase + 8 * XSLOT <= NLEN);
        if (inter) {
            const int g0 = xbase + 8 * T0;
            A0a = *(const f32x4*)(xr + g0);
            A0b = *(const f32x4*)(xr + g0 + 4);
            B0a = *(const f32x4*)(xi + g0);
            B0b = *(const f32x4*)(xi + g0 + 4);
            if (hasT1) {
                const int g1 = xbase + 8 * T1;
                A1a = *(const f32x4*)(xr + g1);
                A1b = *(const f32x4*)(xr + g1 + 4);
                B1a = *(const f32x4*)(xi + g1);
                B1b = *(const f32x4*)(xi + g1 + 4);
            }
        }
    };

    /* convert + write staged regs into LDS buffer (edge tiles: full gather here) */
    auto write_buf = [&](int buf, int tile, bool inter) {
        if (inter) {
            half8 vr, vi;
            #pragma unroll
            for (int e = 0; e < 4; ++e) {
                vr[e] = (_Float16)A0a[e]; vr[e + 4] = (_Float16)A0b[e];
                vi[e] = (_Float16)B0a[e]; vi[e + 4] = (_Float16)B0b[e];
            }
            const int Ts0 = swz(T0);
            lx[buf][0][Ts0] = vr;
            lx[buf][1][Ts0] = vi;
            if (hasT1) {
                half8 wr2, wi2;
                #pragma unroll
                for (int e = 0; e < 4; ++e) {
                    wr2[e] = (_Float16)A1a[e]; wr2[e + 4] = (_Float16)A1b[e];
                    wi2[e] = (_Float16)B1a[e]; wi2[e + 4] = (_Float16)B1b[e];
                }
                const int Ts1 = swz(T1);
                lx[buf][0][Ts1] = wr2;
                lx[buf][1][Ts1] = wi2;
            }
        } else {
            const int xbase = tile * BT - MPAD;
            for (int s = 0; s < 2; ++s) {
                const int T = s ? T1 : T0;
                if (s && !hasT1) break;
                const int g = xbase + 8 * T;
                half8 vr, vi;
                #pragma unroll
                for (int e = 0; e < 8; ++e) {
                    const int ge = g + e;
                    const bool ok = (ge >= 0) && (ge < NLEN);
                    vr[e] = (_Float16)(ok ? xr[ge] : 0.0f);
                    vi[e] = (_Float16)(ok ? xi[ge] : 0.0f);
                }
                const int Ts = swz(T);
                lx[buf][0][Ts] = vr;
                lx[buf][1][Ts] = vi;
            }
        }
    };

    /* MFMA over one tile from LDS buffer, then store outputs */
    auto compute_store = [&](int buf, int tile) {
        const half8* bre = &lx[buf][0][0];
        const half8* bim = &lx[buf][1][0];
        f32x4 accr[2], acci[2];
        #pragma unroll
        for (int t = 0; t < 2; ++t) { accr[t] = (f32x4)0.0f; acci[t] = (f32x4)0.0f; }

        half8 awr = afr[0];
        half8 awi = afi[0];
        #pragma unroll
        for (int c = 0; c < NCH; ++c) {
            const int cn = (c + 1 < NCH) ? c + 1 : 0;   /* harmless reload on last */
            const half8 nwr = afr[cn * 64];
            const half8 nwi = afi[cn * 64];
            const half8 awin = -awi;                    /* exact fp16 sign flip */
            #pragma unroll
            for (int t = 0; t < 2; ++t) {
                const int Ts = swz(sT0 + 32 * t + 4 * c);
                const half8 br = bre[Ts];
                const half8 bi = bim[Ts];
                accr[t] = __builtin_amdgcn_mfma_f32_16x16x32_f16(awr,  br, accr[t], 0, 0, 0);
                accr[t] = __builtin_amdgcn_mfma_f32_16x16x32_f16(awin, bi, accr[t], 0, 0, 0);
                acci[t] = __builtin_amdgcn_mfma_f32_16x16x32_f16(awr,  bi, acci[t], 0, 0, 0);
                acci[t] = __builtin_amdgcn_mfma_f32_16x16x32_f16(awi,  br, acci[t], 0, 0, 0);
            }
            awr = nwr; awi = nwi;
        }

        const int t0    = tile * BT;
        const int obase = t0 + 512 * wv + 16 * n15 + 4 * lg;
        #pragma unroll
        for (int t = 0; t < 2; ++t) {
            const int tbase = t0 + 512 * wv + 256 * t;
            if (tbase < OUTLEN) {
                const int pos = obase + 256 * t;
                *(f32x4*)(out + pos)          = accr[t];
                *(f32x4*)(out + OUTLEN + pos) = acci[t];
            }
        }
    };

    /* ---- prologue: stage tile 0 into buf 0 ---- */
    bool inter0;
    issue_loads(tile0, inter0);
    write_buf(0, tile0, inter0);

    /* ---- pipelined tile loop: one barrier per tile ---- */
    for (int j = 0; j < ntile; ++j) {
        __syncthreads();                       /* buf[j&1] visible to all waves */
        const int nj = j + 1;
        bool interN = false;
        if (nj < ntile) issue_loads(tile0 + nj, interN);   /* T14: issue early  */
        compute_store(j & 1, tile0 + j);                   /* MFMA + store      */
        if (nj < ntile) write_buf(nj & 1, tile0 + nj, interN); /* write late    */
    }
}

/* ---------- fallback (exact R3 shape): af in LDS, BT=4096 ---------- */
#define FBT    4096
#define FNBLK  ((OUTLEN + FBT - 1) / FBT)
#define FXSLOT ((FBT + 288) / 8)
#define FXPAD  556

__global__ __launch_bounds__(TPB, 4) void cconv_local(
    const float* __restrict__ xr, const float* __restrict__ xi,
    const float* __restrict__ wr, const float* __restrict__ wi,
    float* __restrict__ out)
{
    __shared__ half8 lx[2][FXPAD];
    __shared__ half8 af[2][NCH][64];

    const int tid   = threadIdx.x;
    const int wv    = tid >> 6;
    const int lane  = tid & 63;
    const int n15   = lane & 15;
    const int lg    = lane >> 4;
    const int t0    = blockIdx.x * FBT;
    const int xbase = t0 - MPAD;

    for (int i = tid; i < AFSLOT; i += TPB) {
        const int comp = i / (NCH * 64);
        const int rem  = i % (NCH * 64);
        const int c    = rem >> 6;
        const int l    = rem & 63;
        const int row  = l & 15;
        const int jb   = 32 * c + 8 * (l >> 4);
        const float* wp = comp ? wi : wr;
        half8 v;
        #pragma unroll
        for (int e = 0; e < 8; ++e) {
            const int k = jb + e - row;
            const float f = (k >= 0 && k < KTAPS) ? wp[k] : 0.0f;
            v[e] = (_Float16)f;
        }
        af[comp][c][l] = v;
    }
    {
        for (int T = tid; T < FXSLOT; T += TPB) {
            const int g = xbase + 8 * T;
            half8 vr, vi;
            if (g >= 0 && g + 8 <= NLEN) {
                const f32x4 a0 = *(const f32x4*)(xr + g);
                const f32x4 a1 = *(const f32x4*)(xr + g + 4);
                const f32x4 b0 = *(const f32x4*)(xi + g);
                const f32x4 b1 = *(const f32x4*)(xi + g + 4);
                #pragma unroll
                for (int e = 0; e < 4; ++e) {
                    vr[e]     = (_Float16)a0[e];
                    vr[e + 4] = (_Float16)a1[e];
                    vi[e]     = (_Float16)b0[e];
                    vi[e + 4] = (_Float16)b1[e];
                }
            } else {
                #pragma unroll
                for (int e = 0; e < 8; ++e) {
                    const int ge = g + e;
                    const bool ok = (ge >= 0) && (ge < NLEN);
                    vr[e] = (_Float16)(ok ? xr[ge] : 0.0f);
                    vi[e] = (_Float16)(ok ? xi[ge] : 0.0f);
                }
            }
            const int Ts = swz(T);
            lx[0][Ts] = vr;
            lx[1][Ts] = vi;
        }
    }
    __syncthreads();

    f32x4 accr[4], acci[4];
    #pragma unroll
    for (int t = 0; t < 4; ++t) { accr[t] = (f32x4)0.0f; acci[t] = (f32x4)0.0f; }

    const int sT0 = 128 * wv + 2 * n15 + lg;

    #pragma unroll
    for (int c = 0; c < NCH; ++c) {
        const half8 awr  = af[0][c][lane];
        const half8 awi  = af[1][c][lane];
        const half8 awin = -awi;
        #pragma unroll
        for (int t = 0; t < 4; ++t) {
            const int Ts = swz(sT0 + 32 * t + 4 * c);
            const half8 br = lx[0][Ts];
            const half8 bi = lx[1][Ts];
            accr[t] = __builtin_amdgcn_mfma_f32_16x16x32_f16(awr,  br, accr[t], 0, 0, 0);
            accr[t] = __builtin_amdgcn_mfma_f32_16x16x32_f16(awin, bi, accr[t], 0, 0, 0);
            acci[t] = __builtin_amdgcn_mfma_f32_16x16x32_f16(awr,  bi, acci[t], 0, 0, 0);
            acci[t] = __builtin_amdgcn_mfma_f32_16x16x32_f16(awi,  br, acci[t], 0, 0, 0);
        }
    }

    const int obase = t0 + 1024 * wv + 16 * n15 + 4 * lg;
    #pragma unroll
    for (int t = 0; t < 4; ++t) {
        const int tbase = t0 + 1024 * wv + 256 * t;
        if (tbase < OUTLEN) {
            const int pos = obase + 256 * t;
            *(f32x4*)(out + pos)          = accr[t];
            *(f32x4*)(out + OUTLEN + pos) = acci[t];
        }
    }
}

extern "C" void kernel_launch(void* const* d_in, const int* in_sizes, int n_in,
                              void* d_out, int out_size, void* d_ws, size_t ws_size,
                              hipStream_t stream) {
    const float* xr = (const float*)d_in[0];
    const float* xi = (const float*)d_in[1];
    const float* wr = (const float*)d_in[2];
    const float* wi = (const float*)d_in[3];
    float* o = (float*)d_out;
    if (ws_size >= (size_t)AFSLOT * 16) {
        build_af<<<1, TPB, 0, stream>>>(wr, wi, (half8*)d_ws);
        cconv_db<<<NBLKP, TPB, 0, stream>>>(xr, xi, (const half8*)d_ws, o);
    } else {
        cconv_local<<<FNBLK, TPB, 0, stream>>>(xr, xi, wr, wi, o);
    }
}

// Round 8
// 43.186 us; speedup vs baseline: 1.4894x; 1.4894x over previous
//
#include <hip/hip_runtime.h>

typedef _Float16 half8 __attribute__((ext_vector_type(8)));
typedef float    f32x4 __attribute__((ext_vector_type(4)));

#define NLEN   8388608
#define KTAPS  257
#define MPAD   256
#define OUTLEN (NLEN + MPAD)        /* 8388864 */
#define TPB    256
#define BT     2048                 /* complex outputs per tile */
#define NTILES ((OUTLEN + BT - 1) / BT)   /* 4097 */
#define TPT    4                    /* tiles per block */
#define NBLKP  ((NTILES + TPT - 1) / TPT) /* 1025 */
#define NCH    9                    /* K chunks of 32 -> GEMM-K = 288 */
#define XELEM  (BT + 288)           /* staged elems per component: 2336 */
#define XSLOT  (XELEM / 8)          /* 292 fp16 16B slots */
#define XPAD   300
#define CH     (XELEM / 4)          /* 584 fp32 16B chunks per component */
#define AFSLOT (2 * NCH * 64)       /* 1152 half8 slots = 18432 B */

typedef const __attribute__((address_space(1))) void gv_t;
typedef __attribute__((address_space(3))) void lv_t;

__device__ __forceinline__ int swz(int t) { return t ^ ((t >> 3) & 7); }

/* ---------- pre-kernel: weight-fragment table in global ws ---------- */
__global__ __launch_bounds__(TPB) void build_af(
    const float* __restrict__ wr, const float* __restrict__ wi,
    half8* __restrict__ af)
{
    for (int i = threadIdx.x; i < AFSLOT; i += TPB) {
        const int comp = i / (NCH * 64);
        const int rem  = i % (NCH * 64);
        const int c    = rem >> 6;
        const int l    = rem & 63;
        const int row  = l & 15;
        const int jb   = 32 * c + 8 * (l >> 4);
        const float* wp = comp ? wi : wr;
        half8 v;
        #pragma unroll
        for (int e = 0; e < 8; ++e) {
            const int k = jb + e - row;
            const float f = (k >= 0 && k < KTAPS) ? wp[k] : 0.0f;
            v[e] = (_Float16)f;
        }
        af[i] = v;
    }
}

/* ---------- main: 4 tiles/block, gload_lds pipeline, dbuf fp16 LDS ---------- */
__global__ __launch_bounds__(TPB, 4) void cconv_pipe(
    const float* __restrict__ xr, const float* __restrict__ xi,
    const half8* __restrict__ af, float* __restrict__ out)
{
    __shared__ f32x4 fx[2][CH];          /* fp32 staging, linear (gload_lds dest) */
    __shared__ half8 lx[2][2][XPAD];     /* fp16 window  [buf][comp][slot]        */

    const int tid   = threadIdx.x;
    const int wv    = tid >> 6;
    const int lane  = tid & 63;
    const int n15   = lane & 15;
    const int lg    = lane >> 4;
    const int wb    = tid & ~63;         /* wave-uniform chunk base               */
    const int tile0 = blockIdx.x * TPT;
    const int ntile = (NTILES - tile0 < TPT) ? (NTILES - tile0) : TPT;
    const int sT0   = 64 * wv + 2 * n15 + lg;
    const half8* afr = af + lane;
    const half8* afi = af + NCH * 64 + lane;

    /* ======== phase helpers as plain macros (straight-line, named locals) ======== */

    /* issue async global->LDS fp32 stage for tile with window base XB (interior only) */
#define ISSUE_STAGE(XB)                                                           \
    {                                                                             \
        _Pragma("unroll")                                                         \
        for (int c_ = 0; c_ < 2; ++c_) {                                          \
            const float* src_ = c_ ? xi : xr;                                     \
            _Pragma("unroll")                                                     \
            for (int it_ = 0; it_ < 3; ++it_) {                                   \
                const int T_ = it_ * TPB + tid;                                   \
                if (T_ < CH) {                                                    \
                    __builtin_amdgcn_global_load_lds(                             \
                        (gv_t*)(src_ + (XB) + 4 * T_),                            \
                        (lv_t*)&fx[c_][it_ * TPB + wb], 16, 0, 0);                \
                }                                                                 \
            }                                                                     \
        }                                                                         \
    }

    /* fp32 LDS -> fp16 swizzled LDS (interior tiles) */
#define CONVERT_PASS(BUF)                                                         \
    {                                                                             \
        _Pragma("unroll")                                                         \
        for (int it_ = 0; it_ < 2; ++it_) {                                       \
            const int s_ = it_ * TPB + tid;                                       \
            if (s_ < XSLOT) {                                                     \
                const int ss_ = swz(s_);                                          \
                _Pragma("unroll")                                                 \
                for (int c_ = 0; c_ < 2; ++c_) {                                  \
                    const f32x4 a_ = fx[c_][2 * s_];                              \
                    const f32x4 b_ = fx[c_][2 * s_ + 1];                          \
                    half8 v_;                                                     \
                    _Pragma("unroll")                                             \
                    for (int e_ = 0; e_ < 4; ++e_) {                              \
                        v_[e_]     = (_Float16)a_[e_];                            \
                        v_[e_ + 4] = (_Float16)b_[e_];                            \
                    }                                                             \
                    lx[BUF][c_][ss_] = v_;                                        \
                }                                                                 \
            }                                                                     \
        }                                                                         \
    }

    /* edge tiles: predicated scalar gather straight into fp16 LDS */
#define STAGE_EDGE(BUF, XB)                                                       \
    {                                                                             \
        for (int T_ = tid; T_ < XSLOT; T_ += TPB) {                               \
            const int g_ = (XB) + 8 * T_;                                         \
            half8 vr_, vi_;                                                       \
            _Pragma("unroll")                                                     \
            for (int e_ = 0; e_ < 8; ++e_) {                                      \
                const int ge_ = g_ + e_;                                          \
                const bool ok_ = (ge_ >= 0) && (ge_ < NLEN);                      \
                vr_[e_] = (_Float16)(ok_ ? xr[ge_] : 0.0f);                       \
                vi_[e_] = (_Float16)(ok_ ? xi[ge_] : 0.0f);                       \
            }                                                                     \
            const int Ts_ = swz(T_);                                              \
            lx[BUF][0][Ts_] = vr_;                                                \
            lx[BUF][1][Ts_] = vi_;                                                \
        }                                                                         \
    }

    /* MFMA over one tile + store */
#define COMPUTE_STORE(BUF, TILE)                                                  \
    {                                                                             \
        f32x4 accr0 = (f32x4)0.0f, accr1 = (f32x4)0.0f;                           \
        f32x4 acci0 = (f32x4)0.0f, acci1 = (f32x4)0.0f;                           \
        half8 awr_ = afr[0];                                                      \
        half8 awi_ = afi[0];                                                      \
        _Pragma("unroll")                                                         \
        for (int c_ = 0; c_ < NCH; ++c_) {                                        \
            const int cn_ = (c_ + 1 < NCH) ? c_ + 1 : 0;                          \
            const half8 nwr_ = afr[cn_ * 64];                                     \
            const half8 nwi_ = afi[cn_ * 64];                                     \
            const half8 awin_ = -awi_;                                            \
            const int Ts0_ = swz(sT0 + 4 * c_);                                   \
            const int Ts1_ = swz(sT0 + 32 + 4 * c_);                              \
            const half8 br0_ = lx[BUF][0][Ts0_];                                  \
            const half8 bi0_ = lx[BUF][1][Ts0_];                                  \
            const half8 br1_ = lx[BUF][0][Ts1_];                                  \
            const half8 bi1_ = lx[BUF][1][Ts1_];                                  \
            accr0 = __builtin_amdgcn_mfma_f32_16x16x32_f16(awr_,  br0_, accr0, 0, 0, 0); \
            accr0 = __builtin_amdgcn_mfma_f32_16x16x32_f16(awin_, bi0_, accr0, 0, 0, 0); \
            acci0 = __builtin_amdgcn_mfma_f32_16x16x32_f16(awr_,  bi0_, acci0, 0, 0, 0); \
            acci0 = __builtin_amdgcn_mfma_f32_16x16x32_f16(awi_,  br0_, acci0, 0, 0, 0); \
            accr1 = __builtin_amdgcn_mfma_f32_16x16x32_f16(awr_,  br1_, accr1, 0, 0, 0); \
            accr1 = __builtin_amdgcn_mfma_f32_16x16x32_f16(awin_, bi1_, accr1, 0, 0, 0); \
            acci1 = __builtin_amdgcn_mfma_f32_16x16x32_f16(awr_,  bi1_, acci1, 0, 0, 0); \
            acci1 = __builtin_amdgcn_mfma_f32_16x16x32_f16(awi_,  br1_, acci1, 0, 0, 0); \
            awr_ = nwr_; awi_ = nwi_;                                             \
        }                                                                         \
        const int t0_    = (TILE) * BT;                                           \
        const int obase_ = t0_ + 512 * wv + 16 * n15 + 4 * lg;                    \
        if (t0_ + 512 * wv < OUTLEN) {                                            \
            *(f32x4*)(out + obase_)          = accr0;                             \
            *(f32x4*)(out + OUTLEN + obase_) = acci0;                             \
        }                                                                         \
        if (t0_ + 512 * wv + 256 < OUTLEN) {                                      \
            *(f32x4*)(out + obase_ + 256)          = accr1;                       \
            *(f32x4*)(out + OUTLEN + obase_ + 256) = acci1;                       \
        }                                                                         \
    }

    /* ======== prologue: stage tile0 ======== */
    {
        const int xb = tile0 * BT - MPAD;
        const bool intr = (xb >= 0) && (xb + 4 * CH <= NLEN);
        if (intr) ISSUE_STAGE(xb);
        __syncthreads();                 /* vmcnt drained by barrier semantics */
        if (intr) { CONVERT_PASS(0) } else { STAGE_EDGE(0, xb) }
        __syncthreads();
    }

    /* ======== pipelined tile loop ======== */
    for (int j = 0; j < ntile; ++j) {
        const int xbn   = (tile0 + j + 1) * BT - MPAD;
        const bool hasN = (j + 1 < ntile);
        const bool iN   = hasN && (xbn >= 0) && (xbn + 4 * CH <= NLEN);
        if (iN) ISSUE_STAGE(xbn);                 /* overlaps MFMA below      */
        COMPUTE_STORE(j & 1, tile0 + j);
        __syncthreads();                          /* drains vmcnt(0): loads landed */
        if (hasN) {
            if (iN) { CONVERT_PASS((j + 1) & 1) } else { STAGE_EDGE((j + 1) & 1, xbn) }
        }
        __syncthreads();
    }
}

/* ---------- fallback (R3 shape): af in LDS, BT=4096, single stage ---------- */
#define FBT    4096
#define FNBLK  ((OUTLEN + FBT - 1) / FBT)
#define FXSLOT ((FBT + 288) / 8)
#define FXPAD  556

__global__ __launch_bounds__(TPB, 4) void cconv_local(
    const float* __restrict__ xr, const float* __restrict__ xi,
    const float* __restrict__ wr, const float* __restrict__ wi,
    float* __restrict__ out)
{
    __shared__ half8 lx[2][FXPAD];
    __shared__ half8 af[2][NCH][64];

    const int tid   = threadIdx.x;
    const int wv    = tid >> 6;
    const int lane  = tid & 63;
    const int n15   = lane & 15;
    const int lg    = lane >> 4;
    const int t0    = blockIdx.x * FBT;
    const int xbase = t0 - MPAD;

    for (int i = tid; i < AFSLOT; i += TPB) {
        const int comp = i / (NCH * 64);
        const int rem  = i % (NCH * 64);
        const int c    = rem >> 6;
        const int l    = rem & 63;
        const int row  = l & 15;
        const int jb   = 32 * c + 8 * (l >> 4);
        const float* wp = comp ? wi : wr;
        half8 v;
        #pragma unroll
        for (int e = 0; e < 8; ++e) {
            const int k = jb + e - row;
            const float f = (k >= 0 && k < KTAPS) ? wp[k] : 0.0f;
            v[e] = (_Float16)f;
        }
        af[comp][c][l] = v;
    }
    for (int T = tid; T < FXSLOT; T += TPB) {
        const int g = xbase + 8 * T;
        half8 vr, vi;
        if (g >= 0 && g + 8 <= NLEN) {
            const f32x4 a0 = *(const f32x4*)(xr + g);
            const f32x4 a1 = *(const f32x4*)(xr + g + 4);
            const f32x4 b0 = *(const f32x4*)(xi + g);
            const f32x4 b1 = *(const f32x4*)(xi + g + 4);
            #pragma unroll
            for (int e = 0; e < 4; ++e) {
                vr[e]     = (_Float16)a0[e];
                vr[e + 4] = (_Float16)a1[e];
                vi[e]     = (_Float16)b0[e];
                vi[e + 4] = (_Float16)b1[e];
            }
        } else {
            #pragma unroll
            for (int e = 0; e < 8; ++e) {
                const int ge = g + e;
                const bool ok = (ge >= 0) && (ge < NLEN);
                vr[e] = (_Float16)(ok ? xr[ge] : 0.0f);
                vi[e] = (_Float16)(ok ? xi[ge] : 0.0f);
            }
        }
        const int Ts = swz(T);
        lx[0][Ts] = vr;
        lx[1][Ts] = vi;
    }
    __syncthreads();

    f32x4 accr[4], acci[4];
    #pragma unroll
    for (int t = 0; t < 4; ++t) { accr[t] = (f32x4)0.0f; acci[t] = (f32x4)0.0f; }

    const int sT0 = 128 * wv + 2 * n15 + lg;

    #pragma unroll
    for (int c = 0; c < NCH; ++c) {
        const half8 awr  = af[0][c][lane];
        const half8 awi  = af[1][c][lane];
        const half8 awin = -awi;
        #pragma unroll
        for (int t = 0; t < 4; ++t) {
            const int Ts = swz(sT0 + 32 * t + 4 * c);
            const half8 br = lx[0][Ts];
            const half8 bi = lx[1][Ts];
            accr[t] = __builtin_amdgcn_mfma_f32_16x16x32_f16(awr,  br, accr[t], 0, 0, 0);
            accr[t] = __builtin_amdgcn_mfma_f32_16x16x32_f16(awin, bi, accr[t], 0, 0, 0);
            acci[t] = __builtin_amdgcn_mfma_f32_16x16x32_f16(awr,  bi, acci[t], 0, 0, 0);
            acci[t] = __builtin_amdgcn_mfma_f32_16x16x32_f16(awi,  br, acci[t], 0, 0, 0);
        }
    }

    const int obase = t0 + 1024 * wv + 16 * n15 + 4 * lg;
    #pragma unroll
    for (int t = 0; t < 4; ++t) {
        const int tbase = t0 + 1024 * wv + 256 * t;
        if (tbase < OUTLEN) {
            const int pos = obase + 256 * t;
            *(f32x4*)(out + pos)          = accr[t];
            *(f32x4*)(out + OUTLEN + pos) = acci[t];
        }
    }
}

extern "C" void kernel_launch(void* const* d_in, const int* in_sizes, int n_in,
                              void* d_out, int out_size, void* d_ws, size_t ws_size,
                              hipStream_t stream) {
    const float* xr = (const float*)d_in[0];
    const float* xi = (const float*)d_in[1];
    const float* wr = (const float*)d_in[2];
    const float* wi = (const float*)d_in[3];
    float* o = (float*)d_out;
    if (ws_size >= (size_t)AFSLOT * 16) {
        build_af<<<1, TPB, 0, stream>>>(wr, wi, (half8*)d_ws);
        cconv_pipe<<<NBLKP, TPB, 0, stream>>>(xr, xi, (const half8*)d_ws, o);
    } else {
        cconv_local<<<FNBLK, TPB, 0, stream>>>(xr, xi, wr, wi, o);
    }
}